// Round 1
// baseline (1989.238 us; speedup 1.0000x reference)
//
#include <hip/hip_runtime.h>
#include <hip/hip_bf16.h>

#define NN 50000
#define NEDGE 400000
#define CDIM 128
#define NSP 50048  // padded row stride for attn1 score matrix

typedef short bf16x8 __attribute__((ext_vector_type(8)));
typedef short bf16x4 __attribute__((ext_vector_type(4)));
typedef float f32x4 __attribute__((ext_vector_type(4)));

__device__ __forceinline__ short f2b(float f) {
  union { float f; unsigned u; } a; a.f = f;
  unsigned u = a.u;
  u += 0x7fffu + ((u >> 16) & 1u);   // RNE
  return (short)(u >> 16);
}
__device__ __forceinline__ float b2f(short s) {
  union { unsigned u; float f; } a; a.u = ((unsigned)(unsigned short)s) << 16;
  return a.f;
}
__device__ __forceinline__ float geluf(float x) {
  return 0.5f * x * (1.0f + erff(x * 0.7071067811865475f));
}
__device__ __forceinline__ f32x4 mfma16(bf16x8 a, bf16x8 b, f32x4 c) {
  return __builtin_amdgcn_mfma_f32_16x16x32_bf16(a, b, c, 0, 0, 0);
}

// ---------------- prep: convert weights to bf16, fold scales ----------------
__global__ __launch_bounds__(256) void prep_kernel(
    const float* few1, const float* few2, const float* fnw1, const float* fnw2,
    const float* k1w, const float* v1w, const float* q2w,
    const float* k1b, const float* v1b, const float* q2b,
    const float* linw,
    short* wb1, short* wb2, short* wn1, short* wn2,
    short* wkvq, float* bkvq, short* wlin)
{
  int i = blockIdx.x * blockDim.x + threadIdx.x;
  int nthr = gridDim.x * blockDim.x;
  const float scale = 0.0883883476483184f;  // 128^-0.5
  for (int idx = i; idx < 98304; idx += nthr) wb1[idx] = f2b(few1[idx]);
  for (int idx = i; idx < 32768; idx += nthr) wb2[idx] = f2b(few2[idx]);
  for (int idx = i; idx < 65536; idx += nthr) wn1[idx] = f2b(fnw1[idx]);
  for (int idx = i; idx < 32768; idx += nthr) wn2[idx] = f2b(fnw2[idx]);
  for (int idx = i; idx < 16384; idx += nthr) {
    wkvq[idx]         = f2b(k1w[idx]);
    wkvq[16384 + idx] = f2b(v1w[idx]);
    wkvq[32768 + idx] = f2b(q2w[idx] * scale);  // fold attn2 scale into Q2
    wlin[idx]         = f2b(linw[idx]);
  }
  for (int idx = i; idx < 128; idx += nthr) {
    bkvq[idx]       = k1b[idx];
    bkvq[128 + idx] = v1b[idx];
    bkvq[256 + idx] = q2b[idx] * scale;
  }
}

// ---------------- Q1 = (Qp @ q1_w^T + b) * scale, bf16 ----------------
__global__ __launch_bounds__(256) void q1_kernel(
    const float* Qp, const float* q1w, const float* q1b, short* q1bf)
{
  int idx = blockIdx.x * 256 + threadIdx.x;  // 8192
  int m = idx >> 7, n = idx & 127;
  const float scale = 0.0883883476483184f;
  float s = q1b[n];
  const float* qr = Qp + m * CDIM;
  const float* wr = q1w + n * CDIM;
  for (int k = 0; k < CDIM; k++) s += qr[k] * wr[k];
  q1bf[idx] = f2b(s * scale);
}

// ---------------- edge MLP + LN + E_out + scatter-add ----------------
__global__ __launch_bounds__(256) void edge_kernel(
    const float* __restrict__ V, const float* __restrict__ E,
    const int* __restrict__ edges,
    const short* __restrict__ wb1, const float* __restrict__ fb1,
    const short* __restrict__ wb2, const float* __restrict__ fb2,
    const float* __restrict__ feg, const float* __restrict__ febe,
    const float* __restrict__ a2p,
    float* __restrict__ accn, float* __restrict__ cnt,
    float* __restrict__ outE)
{
  __shared__ short xs[64 * 392];   // gathered [senders|recv|E], bf16; aliased as hs (stride 264)
  __shared__ float redS[64][4], redQ[64][4];
  __shared__ int recvl[64];
  const int t = threadIdx.x;
  const int e0 = blockIdx.x * 64;
  if (t < 64) recvl[t] = edges[(e0 + t) * 2 + 1];
#pragma unroll
  for (int p = 0; p < 24; p++) {
    int fid = p * 256 + t;        // 6144 float4 slots: 64 rows x 96
    int row = fid / 96;
    int c = fid - row * 96;
    int seg = c >> 5;
    int c4 = c & 31;
    const float* src;
    if (seg == 0)      src = V + (size_t)edges[(e0 + row) * 2]     * CDIM + c4 * 4;
    else if (seg == 1) src = V + (size_t)edges[(e0 + row) * 2 + 1] * CDIM + c4 * 4;
    else               src = E + (size_t)(e0 + row) * CDIM + c4 * 4;
    f32x4 v = *(const f32x4*)src;
    bf16x4 bb; bb[0] = f2b(v[0]); bb[1] = f2b(v[1]); bb[2] = f2b(v[2]); bb[3] = f2b(v[3]);
    *(bf16x4*)(&xs[row * 392 + seg * 128 + c4 * 4]) = bb;
  }
  __syncthreads();
  const int lane = t & 63, wid = t >> 6;
  const int lr = lane & 15;
  const int g4 = (lane >> 4) * 4;
  const int lk = (lane >> 4) * 8;
  // ---- layer 1: [64,384] @ [384 -> 256], N-split across waves (64 cols each)
  f32x4 acc1[4][4];
#pragma unroll
  for (int nt = 0; nt < 4; nt++) {
    float bv = fb1[wid * 64 + nt * 16 + lr];
#pragma unroll
    for (int mt = 0; mt < 4; mt++) acc1[mt][nt] = (f32x4){bv, bv, bv, bv};
  }
  for (int s = 0; s < 12; s++) {
    bf16x8 af[4];
#pragma unroll
    for (int mt = 0; mt < 4; mt++)
      af[mt] = *(const bf16x8*)(&xs[(mt * 16 + lr) * 392 + s * 32 + lk]);
#pragma unroll
    for (int nt = 0; nt < 4; nt++) {
      bf16x8 bf = *(const bf16x8*)(wb1 + (size_t)(wid * 64 + nt * 16 + lr) * 384 + s * 32 + lk);
#pragma unroll
      for (int mt = 0; mt < 4; mt++) acc1[mt][nt] = mfma16(af[mt], bf, acc1[mt][nt]);
    }
  }
  __syncthreads();          // all waves done reading xs before hs overwrite
  short* hs = xs;           // reuse as [64][264] bf16
#pragma unroll
  for (int mt = 0; mt < 4; mt++)
#pragma unroll
    for (int nt = 0; nt < 4; nt++)
#pragma unroll
      for (int i = 0; i < 4; i++)
        hs[(mt * 16 + g4 + i) * 264 + wid * 64 + nt * 16 + lr] = f2b(geluf(acc1[mt][nt][i]));
  __syncthreads();
  // ---- layer 2: [64,256] @ [256 -> 128], N-split (32 cols per wave)
  f32x4 acc2[4][2];
#pragma unroll
  for (int nt = 0; nt < 2; nt++) {
    float bv = fb2[wid * 32 + nt * 16 + lr];
#pragma unroll
    for (int mt = 0; mt < 4; mt++) acc2[mt][nt] = (f32x4){bv, bv, bv, bv};
  }
  for (int s = 0; s < 8; s++) {
    bf16x8 af[4];
#pragma unroll
    for (int mt = 0; mt < 4; mt++)
      af[mt] = *(const bf16x8*)(&hs[(mt * 16 + lr) * 264 + s * 32 + lk]);
#pragma unroll
    for (int nt = 0; nt < 2; nt++) {
      bf16x8 bf = *(const bf16x8*)(wb2 + (size_t)(wid * 32 + nt * 16 + lr) * 256 + s * 32 + lk);
#pragma unroll
      for (int mt = 0; mt < 4; mt++) acc2[mt][nt] = mfma16(af[mt], bf, acc2[mt][nt]);
    }
  }
  // ---- LayerNorm across 128 cols (cross-wave via LDS partials)
#pragma unroll
  for (int mt = 0; mt < 4; mt++)
#pragma unroll
    for (int i = 0; i < 4; i++) {
      float s1 = acc2[mt][0][i] + acc2[mt][1][i];
      float s2 = acc2[mt][0][i] * acc2[mt][0][i] + acc2[mt][1][i] * acc2[mt][1][i];
#pragma unroll
      for (int m = 1; m <= 8; m <<= 1) { s1 += __shfl_xor(s1, m); s2 += __shfl_xor(s2, m); }
      if (lr == 0) { redS[mt * 16 + g4 + i][wid] = s1; redQ[mt * 16 + g4 + i][wid] = s2; }
    }
  __syncthreads();
  float a2v = a2p[0];
  float sa2 = a2v / (1.0f + __expf(-a2v));
  float mean[4][4], rstd[4][4];
#pragma unroll
  for (int mt = 0; mt < 4; mt++)
#pragma unroll
    for (int i = 0; i < 4; i++) {
      int row = mt * 16 + g4 + i;
      float s1 = redS[row][0] + redS[row][1] + redS[row][2] + redS[row][3];
      float s2 = redQ[row][0] + redQ[row][1] + redQ[row][2] + redQ[row][3];
      float mn = s1 * (1.0f / 128.0f);
      float var = s2 * (1.0f / 128.0f) - mn * mn;
      mean[mt][i] = mn;
      rstd[mt][i] = rsqrtf(var + 1e-5f);
    }
#pragma unroll
  for (int nt = 0; nt < 2; nt++) {
    int col = wid * 32 + nt * 16 + lr;
    float gg = feg[col], bb = febe[col];
#pragma unroll
    for (int mt = 0; mt < 4; mt++)
#pragma unroll
      for (int i = 0; i < 4; i++) {
        int row = mt * 16 + g4 + i;
        float v = (acc2[mt][nt][i] - mean[mt][i]) * rstd[mt][i] * gg + bb;
        size_t ge = (size_t)(e0 + row) * CDIM + col;
        outE[ge] = E[ge] + sa2 * v;
        atomicAdd(&accn[(size_t)recvl[row] * CDIM + col], v);
      }
  }
  if (wid == 0 && lr == 0) {
#pragma unroll
    for (int mt = 0; mt < 4; mt++)
#pragma unroll
      for (int i = 0; i < 4; i++)
        atomicAdd(&cnt[recvl[mt * 16 + g4 + i]], 1.0f);
  }
}

// ---------------- node MLP + gated residual + two LNs -> Vr(f32), W0(bf16) ----------------
__global__ __launch_bounds__(256) void node_kernel(
    const float* __restrict__ V, const float* __restrict__ accn, const float* __restrict__ cnt,
    const short* __restrict__ wn1, const float* __restrict__ fnb1,
    const short* __restrict__ wn2, const float* __restrict__ fnb2,
    const float* __restrict__ fng, const float* __restrict__ fnbe,
    const float* __restrict__ ln1g, const float* __restrict__ ln1b,
    const float* __restrict__ a1p,
    float* __restrict__ Vr, short* __restrict__ W0bf)
{
  __shared__ short xs[64 * 264];
  __shared__ float redS[64][4], redQ[64][4], redS2[64][4], redQ2[64][4];
  const int t = threadIdx.x;
  const int n0 = blockIdx.x * 64;
#pragma unroll
  for (int p = 0; p < 16; p++) {
    int fid = p * 256 + t;
    int row = fid >> 6;
    int c = fid & 63;
    int node = n0 + row; if (node >= NN) node = NN - 1;
    f32x4 v;
    if (c < 32) v = *(const f32x4*)(V + (size_t)node * CDIM + c * 4);
    else {
      v = *(const f32x4*)(accn + (size_t)node * CDIM + (c - 32) * 4);
      float ic = 1.0f / fmaxf(cnt[node], 1.0f);
      v[0] *= ic; v[1] *= ic; v[2] *= ic; v[3] *= ic;
    }
    bf16x4 bb; bb[0] = f2b(v[0]); bb[1] = f2b(v[1]); bb[2] = f2b(v[2]); bb[3] = f2b(v[3]);
    *(bf16x4*)(&xs[row * 264 + c * 4]) = bb;
  }
  __syncthreads();
  const int lane = t & 63, wid = t >> 6;
  const int lr = lane & 15;
  const int g4 = (lane >> 4) * 4;
  const int lk = (lane >> 4) * 8;
  f32x4 acc1[4][4];
#pragma unroll
  for (int nt = 0; nt < 4; nt++) {
    float bv = fnb1[wid * 64 + nt * 16 + lr];
#pragma unroll
    for (int mt = 0; mt < 4; mt++) acc1[mt][nt] = (f32x4){bv, bv, bv, bv};
  }
  for (int s = 0; s < 8; s++) {
    bf16x8 af[4];
#pragma unroll
    for (int mt = 0; mt < 4; mt++)
      af[mt] = *(const bf16x8*)(&xs[(mt * 16 + lr) * 264 + s * 32 + lk]);
#pragma unroll
    for (int nt = 0; nt < 4; nt++) {
      bf16x8 bf = *(const bf16x8*)(wn1 + (size_t)(wid * 64 + nt * 16 + lr) * 256 + s * 32 + lk);
#pragma unroll
      for (int mt = 0; mt < 4; mt++) acc1[mt][nt] = mfma16(af[mt], bf, acc1[mt][nt]);
    }
  }
  __syncthreads();
  short* hs = xs;
#pragma unroll
  for (int mt = 0; mt < 4; mt++)
#pragma unroll
    for (int nt = 0; nt < 4; nt++)
#pragma unroll
      for (int i = 0; i < 4; i++)
        hs[(mt * 16 + g4 + i) * 264 + wid * 64 + nt * 16 + lr] = f2b(geluf(acc1[mt][nt][i]));
  __syncthreads();
  f32x4 acc2[4][2];
#pragma unroll
  for (int nt = 0; nt < 2; nt++) {
    float bv = fnb2[wid * 32 + nt * 16 + lr];
#pragma unroll
    for (int mt = 0; mt < 4; mt++) acc2[mt][nt] = (f32x4){bv, bv, bv, bv};
  }
  for (int s = 0; s < 8; s++) {
    bf16x8 af[4];
#pragma unroll
    for (int mt = 0; mt < 4; mt++)
      af[mt] = *(const bf16x8*)(&hs[(mt * 16 + lr) * 264 + s * 32 + lk]);
#pragma unroll
    for (int nt = 0; nt < 2; nt++) {
      bf16x8 bf = *(const bf16x8*)(wn2 + (size_t)(wid * 32 + nt * 16 + lr) * 256 + s * 32 + lk);
#pragma unroll
      for (int mt = 0; mt < 4; mt++) acc2[mt][nt] = mfma16(af[mt], bf, acc2[mt][nt]);
    }
  }
  // LN over v_emb
#pragma unroll
  for (int mt = 0; mt < 4; mt++)
#pragma unroll
    for (int i = 0; i < 4; i++) {
      float s1 = acc2[mt][0][i] + acc2[mt][1][i];
      float s2 = acc2[mt][0][i] * acc2[mt][0][i] + acc2[mt][1][i] * acc2[mt][1][i];
#pragma unroll
      for (int m = 1; m <= 8; m <<= 1) { s1 += __shfl_xor(s1, m); s2 += __shfl_xor(s2, m); }
      if (lr == 0) { redS[mt * 16 + g4 + i][wid] = s1; redQ[mt * 16 + g4 + i][wid] = s2; }
    }
  __syncthreads();
  float a1v = a1p[0];
  float sa1 = a1v / (1.0f + __expf(-a1v));
  float mean[4][4], rstd[4][4];
#pragma unroll
  for (int mt = 0; mt < 4; mt++)
#pragma unroll
    for (int i = 0; i < 4; i++) {
      int row = mt * 16 + g4 + i;
      float s1 = redS[row][0] + redS[row][1] + redS[row][2] + redS[row][3];
      float s2 = redQ[row][0] + redQ[row][1] + redQ[row][2] + redQ[row][3];
      float mn = s1 * (1.0f / 128.0f);
      float var = s2 * (1.0f / 128.0f) - mn * mn;
      mean[mt][i] = mn; rstd[mt][i] = rsqrtf(var + 1e-5f);
    }
  // Vr = V + silu(a1)*v_emb ; second LN partials over Vr
#pragma unroll
  for (int nt = 0; nt < 2; nt++) {
    int col = wid * 32 + nt * 16 + lr;
    float gg = fng[col], bb = fnbe[col];
#pragma unroll
    for (int mt = 0; mt < 4; mt++)
#pragma unroll
      for (int i = 0; i < 4; i++) {
        int row = mt * 16 + g4 + i;
        int node = n0 + row;
        int nc = node < NN ? node : NN - 1;
        float vemb = (acc2[mt][nt][i] - mean[mt][i]) * rstd[mt][i] * gg + bb;
        float vr = V[(size_t)nc * CDIM + col] + sa1 * vemb;
        acc2[mt][nt][i] = vr;
        if (node < NN) Vr[(size_t)node * CDIM + col] = vr;
      }
  }
#pragma unroll
  for (int mt = 0; mt < 4; mt++)
#pragma unroll
    for (int i = 0; i < 4; i++) {
      float s1 = acc2[mt][0][i] + acc2[mt][1][i];
      float s2 = acc2[mt][0][i] * acc2[mt][0][i] + acc2[mt][1][i] * acc2[mt][1][i];
#pragma unroll
      for (int m = 1; m <= 8; m <<= 1) { s1 += __shfl_xor(s1, m); s2 += __shfl_xor(s2, m); }
      if (lr == 0) { redS2[mt * 16 + g4 + i][wid] = s1; redQ2[mt * 16 + g4 + i][wid] = s2; }
    }
  __syncthreads();
#pragma unroll
  for (int mt = 0; mt < 4; mt++)
#pragma unroll
    for (int i = 0; i < 4; i++) {
      int row = mt * 16 + g4 + i;
      float s1 = redS2[row][0] + redS2[row][1] + redS2[row][2] + redS2[row][3];
      float s2 = redQ2[row][0] + redQ2[row][1] + redQ2[row][2] + redQ2[row][3];
      float mn = s1 * (1.0f / 128.0f);
      float var = s2 * (1.0f / 128.0f) - mn * mn;
      mean[mt][i] = mn; rstd[mt][i] = rsqrtf(var + 1e-5f);
    }
#pragma unroll
  for (int nt = 0; nt < 2; nt++) {
    int col = wid * 32 + nt * 16 + lr;
    float gg = ln1g[col], bb = ln1b[col];
#pragma unroll
    for (int mt = 0; mt < 4; mt++)
#pragma unroll
      for (int i = 0; i < 4; i++) {
        int row = mt * 16 + g4 + i;
        int node = n0 + row;
        if (node < NN)
          W0bf[(size_t)node * CDIM + col] =
              f2b((acc2[mt][nt][i] - mean[mt][i]) * rstd[mt][i] * gg + bb);
      }
  }
}

// ---------------- K1 | V1 | Q2 = W0 @ [k1|v1|q2]^T + b ----------------
__global__ __launch_bounds__(256) void kvq_kernel(
    const short* __restrict__ W0bf, const short* __restrict__ wkvq,
    const float* __restrict__ bkvq,
    short* __restrict__ K1bf, short* __restrict__ V1bf, short* __restrict__ Q2bf)
{
  const int t = threadIdx.x, lane = t & 63, wid = t >> 6;
  const int n0 = blockIdx.x * 64;
  const int m0 = wid * 16, lr = lane & 15, lk = (lane >> 4) * 8;
  f32x4 acc[24];
#pragma unroll
  for (int tt = 0; tt < 24; tt++) {
    float bv = bkvq[tt * 16 + lr];
    acc[tt] = (f32x4){bv, bv, bv, bv};
  }
  int arow = n0 + m0 + lr; if (arow >= NN) arow = NN - 1;
  for (int s = 0; s < 4; s++) {
    bf16x8 a = *(const bf16x8*)(W0bf + (size_t)arow * CDIM + s * 32 + lk);
#pragma unroll
    for (int tt = 0; tt < 24; tt++) {
      bf16x8 b = *(const bf16x8*)(wkvq + (size_t)(tt * 16 + lr) * CDIM + s * 32 + lk);
      acc[tt] = mfma16(a, b, acc[tt]);
    }
  }
  const int r0 = m0 + (lane >> 4) * 4;
#pragma unroll
  for (int tt = 0; tt < 24; tt++) {
    int col = (tt & 7) * 16 + lr;
    short* dst = tt < 8 ? K1bf : (tt < 16 ? V1bf : Q2bf);
#pragma unroll
    for (int i = 0; i < 4; i++) {
      int node = n0 + r0 + i;
      if (node < NN) dst[(size_t)node * CDIM + col] = f2b(acc[tt][i]);
    }
  }
}

// ---------------- attn1 logits: S[64, N] = Q1 @ K1^T (scale folded) ----------------
__global__ __launch_bounds__(256) void s_kernel(
    const short* __restrict__ q1bf, const short* __restrict__ K1bf, float* __restrict__ S)
{
  const int t = threadIdx.x, lane = t & 63, wid = t >> 6;
  const int nb = blockIdx.x * 256 + wid * 64;
  const int lr = lane & 15, lk = (lane >> 4) * 8;
  f32x4 acc[4][4];
#pragma unroll
  for (int mt = 0; mt < 4; mt++)
#pragma unroll
    for (int nt = 0; nt < 4; nt++) acc[mt][nt] = (f32x4){0.f, 0.f, 0.f, 0.f};
  for (int s = 0; s < 4; s++) {
    bf16x8 a[4], b[4];
#pragma unroll
    for (int mt = 0; mt < 4; mt++)
      a[mt] = *(const bf16x8*)(q1bf + (size_t)(mt * 16 + lr) * CDIM + s * 32 + lk);
#pragma unroll
    for (int nt = 0; nt < 4; nt++) {
      int n = nb + nt * 16 + lr; if (n >= NN) n = NN - 1;
      b[nt] = *(const bf16x8*)(K1bf + (size_t)n * CDIM + s * 32 + lk);
    }
#pragma unroll
    for (int mt = 0; mt < 4; mt++)
#pragma unroll
      for (int nt = 0; nt < 4; nt++) acc[mt][nt] = mfma16(a[mt], b[nt], acc[mt][nt]);
  }
  const int g4 = (lane >> 4) * 4;
#pragma unroll
  for (int mt = 0; mt < 4; mt++)
#pragma unroll
    for (int nt = 0; nt < 4; nt++)
#pragma unroll
      for (int i = 0; i < 4; i++) {
        int q = mt * 16 + g4 + i;
        int n = nb + nt * 16 + lr;
        if (n < NN) S[(size_t)q * NSP + n] = acc[mt][nt][i];
      }
}

// ---------------- row softmax over N=50000 ----------------
__global__ __launch_bounds__(256) void softmax_kernel(float* __restrict__ S)
{
  __shared__ float red[8];
  float* row = S + (size_t)blockIdx.x * NSP;
  const int t = threadIdx.x;
  float m = -1e30f;
  for (int n = t; n < NN; n += 256) m = fmaxf(m, row[n]);
  for (int sh = 1; sh < 64; sh <<= 1) m = fmaxf(m, __shfl_xor(m, sh));
  if ((t & 63) == 0) red[t >> 6] = m;
  __syncthreads();
  m = fmaxf(fmaxf(red[0], red[1]), fmaxf(red[2], red[3]));
  float sum = 0.f;
  for (int n = t; n < NN; n += 256) sum += __expf(row[n] - m);
  for (int sh = 1; sh < 64; sh <<= 1) sum += __shfl_xor(sum, sh);
  if ((t & 63) == 0) red[4 + (t >> 6)] = sum;
  __syncthreads();
  sum = red[4] + red[5] + red[6] + red[7];
  float inv = 1.0f / sum;
  for (int n = t; n < NN; n += 256) row[n] = __expf(row[n] - m) * inv;
}

// ---------------- W1 = P @ V1 (split-K + atomics) ----------------
__global__ __launch_bounds__(256) void w1_kernel(
    const float* __restrict__ S, const short* __restrict__ V1bf, float* __restrict__ W1)
{
  const int t = threadIdx.x;
  const int c4 = t & 31;
  const int qb = t >> 5;  // 0..7
  const int chunk = (NN + 127) / 128;  // 391
  int ns = blockIdx.x * chunk;
  int nend = ns + chunk; if (nend > NN) nend = NN;
  f32x4 acc[8];
#pragma unroll
  for (int p = 0; p < 8; p++) acc[p] = (f32x4){0.f, 0.f, 0.f, 0.f};
  for (int n = ns; n < nend; n++) {
    bf16x4 vb = *(const bf16x4*)(V1bf + (size_t)n * CDIM + c4 * 4);
    f32x4 v; v[0] = b2f(vb[0]); v[1] = b2f(vb[1]); v[2] = b2f(vb[2]); v[3] = b2f(vb[3]);
#pragma unroll
    for (int p = 0; p < 8; p++) {
      float pv = S[(size_t)(p * 8 + qb) * NSP + n];
      acc[p][0] += pv * v[0]; acc[p][1] += pv * v[1];
      acc[p][2] += pv * v[2]; acc[p][3] += pv * v[3];
    }
  }
#pragma unroll
  for (int p = 0; p < 8; p++)
#pragma unroll
    for (int j = 0; j < 4; j++)
      atomicAdd(&W1[(size_t)(p * 8 + qb) * CDIM + c4 * 4 + j], acc[p][j]);
}

// ---------------- qkv = W1 @ mha_in_w^T + b ----------------
__global__ __launch_bounds__(256) void qkv_kernel(
    const float* __restrict__ W1, const float* __restrict__ inw,
    const float* __restrict__ inb, float* __restrict__ qkv)
{
  int idx = blockIdx.x * 256 + threadIdx.x;  // 24576
  int m = idx / 384, n = idx - m * 384;
  float s = inb[n];
  const float* wr = inw + (size_t)n * CDIM;
  const float* xr = W1 + (size_t)m * CDIM;
  for (int k = 0; k < CDIM; k++) s += xr[k] * wr[k];
  qkv[idx] = s;
}

// ---------------- per-head self-attention on 64 tokens ----------------
__global__ __launch_bounds__(256) void heads_kernel(
    const float* __restrict__ qkv, float* __restrict__ o)
{
  __shared__ float q[64][33], k[64][33], v[64][33], sc[64][65];
  const int h = blockIdx.x, t = threadIdx.x;
#pragma unroll
  for (int p = 0; p < 8; p++) {
    int idx = p * 256 + t;
    int i = idx >> 5, d = idx & 31;
    q[i][d] = qkv[i * 384 + h * 32 + d];
    k[i][d] = qkv[i * 384 + 128 + h * 32 + d];
    v[i][d] = qkv[i * 384 + 256 + h * 32 + d];
  }
  __syncthreads();
  const float rs = 0.1767766952966369f;  // 32^-0.5
#pragma unroll
  for (int p = 0; p < 16; p++) {
    int idx = p * 256 + t;
    int i = idx >> 6, j = idx & 63;
    float s = 0.f;
    for (int d = 0; d < 32; d++) s += q[i][d] * k[j][d];
    sc[i][j] = s * rs;
  }
  __syncthreads();
  if (t < 64) {
    float m = -1e30f;
    for (int j = 0; j < 64; j++) m = fmaxf(m, sc[t][j]);
    float sum = 0.f;
    for (int j = 0; j < 64; j++) { float e = __expf(sc[t][j] - m); sc[t][j] = e; sum += e; }
    float inv = 1.0f / sum;
    for (int j = 0; j < 64; j++) sc[t][j] *= inv;
  }
  __syncthreads();
#pragma unroll
  for (int p = 0; p < 8; p++) {
    int idx = p * 256 + t;
    int i = idx >> 5, d = idx & 31;
    float s = 0.f;
    for (int j = 0; j < 64; j++) s += sc[i][j] * v[j][d];
    o[i * CDIM + h * 32 + d] = s;
  }
}

// ---------------- W2 = o @ out_w^T + b ----------------
__global__ __launch_bounds__(256) void w2_kernel(
    const float* __restrict__ o, const float* __restrict__ ow,
    const float* __restrict__ ob, float* __restrict__ W2)
{
  int idx = blockIdx.x * 256 + threadIdx.x;  // 8192
  int m = idx >> 7, n = idx & 127;
  float s = ob[n];
  for (int kk = 0; kk < CDIM; kk++) s += o[m * CDIM + kk] * ow[n * CDIM + kk];
  W2[idx] = s;
}

// ---------------- K2 (bf16 [64][128]) and V2^T (bf16 [128][64]) ----------------
__global__ __launch_bounds__(256) void kv2_kernel(
    const float* __restrict__ W2,
    const float* __restrict__ k2w, const float* __restrict__ k2b,
    const float* __restrict__ v2w, const float* __restrict__ v2b,
    short* __restrict__ k2bf, short* __restrict__ v2tbf)
{
  int idx = blockIdx.x * 256 + threadIdx.x;  // 16384
  int which = idx >> 13;
  int r = (idx >> 7) & 63, n = idx & 127;
  const float* w = which ? v2w : k2w;
  float s = which ? v2b[n] : k2b[n];
  for (int kk = 0; kk < CDIM; kk++) s += W2[r * CDIM + kk] * w[n * CDIM + kk];
  if (which) v2tbf[n * 64 + r] = f2b(s);
  else       k2bf[r * CDIM + n] = f2b(s);
}

// ---------------- fused attn2 + gated residual + LN + final linear -> W3 ----------------
__global__ __launch_bounds__(256) void g_kernel(
    const short* __restrict__ Q2bf, const short* __restrict__ k2bf,
    const short* __restrict__ v2tbf,
    const short* __restrict__ wlin, const float* __restrict__ linb,
    const float* __restrict__ ln2g, const float* __restrict__ ln2b,
    const float* __restrict__ Vr, const float* __restrict__ a3p,
    const float* __restrict__ a4p, float* __restrict__ outW)
{
  __shared__ short p_lds[64 * 72];
  __shared__ short t_lds[64 * 136];
  const int t = threadIdx.x, lane = t & 63, wid = t >> 6;
  const int n0 = blockIdx.x * 64;
  const int m0 = wid * 16, lr = lane & 15, lk = (lane >> 4) * 8;
  const int r0 = m0 + (lane >> 4) * 4;
  int arow = n0 + m0 + lr; if (arow >= NN) arow = NN - 1;
  // scores [16 nodes x 64 tokens]
  f32x4 sacc[4];
#pragma unroll
  for (int nt = 0; nt < 4; nt++) sacc[nt] = (f32x4){0.f, 0.f, 0.f, 0.f};
  for (int s = 0; s < 4; s++) {
    bf16x8 a = *(const bf16x8*)(Q2bf + (size_t)arow * CDIM + s * 32 + lk);
#pragma unroll
    for (int nt = 0; nt < 4; nt++) {
      bf16x8 b = *(const bf16x8*)(k2bf + (size_t)(nt * 16 + lr) * CDIM + s * 32 + lk);
      sacc[nt] = mfma16(a, b, sacc[nt]);
    }
  }
  // softmax over 64 tokens per node-row
  float mx[4], sum[4];
#pragma unroll
  for (int i = 0; i < 4; i++) {
    float m = fmaxf(fmaxf(sacc[0][i], sacc[1][i]), fmaxf(sacc[2][i], sacc[3][i]));
#pragma unroll
    for (int sh = 1; sh <= 8; sh <<= 1) m = fmaxf(m, __shfl_xor(m, sh));
    mx[i] = m; sum[i] = 0.f;
  }
#pragma unroll
  for (int nt = 0; nt < 4; nt++)
#pragma unroll
    for (int i = 0; i < 4; i++) {
      float e = __expf(sacc[nt][i] - mx[i]);
      sacc[nt][i] = e; sum[i] += e;
    }
#pragma unroll
  for (int i = 0; i < 4; i++) {
#pragma unroll
    for (int sh = 1; sh <= 8; sh <<= 1) sum[i] += __shfl_xor(sum[i], sh);
    sum[i] = 1.0f / sum[i];
  }
#pragma unroll
  for (int nt = 0; nt < 4; nt++)
#pragma unroll
    for (int i = 0; i < 4; i++)
      p_lds[(r0 + i) * 72 + nt * 16 + lr] = f2b(sacc[nt][i] * sum[i]);
  __syncthreads();
  // W3a = P @ V2
  f32x4 oacc[8];
#pragma unroll
  for (int tt = 0; tt < 8; tt++) oacc[tt] = (f32x4){0.f, 0.f, 0.f, 0.f};
  for (int s = 0; s < 2; s++) {
    bf16x8 a = *(const bf16x8*)(&p_lds[(m0 + lr) * 72 + s * 32 + lk]);
#pragma unroll
    for (int tt = 0; tt < 8; tt++) {
      bf16x8 b = *(const bf16x8*)(v2tbf + (size_t)(tt * 16 + lr) * 64 + s * 32 + lk);
      oacc[tt] = mfma16(a, b, oacc[tt]);
    }
  }
  float a3v = a3p[0]; float sa3 = a3v / (1.0f + __expf(-a3v));
  float a4v = a4p[0]; float sa4 = a4v / (1.0f + __expf(-a4v));
  float w2r[8][4];
  float sum2[4] = {0.f, 0.f, 0.f, 0.f}, sq2[4] = {0.f, 0.f, 0.f, 0.f};
#pragma unroll
  for (int tt = 0; tt < 8; tt++) {
    int col = tt * 16 + lr;
#pragma unroll
    for (int i = 0; i < 4; i++) {
      int node = n0 + r0 + i;
      int nc = node < NN ? node : NN - 1;
      float vr = Vr[(size_t)nc * CDIM + col];
      float w = vr + sa3 * oacc[tt][i];
      w2r[tt][i] = w;
      sum2[i] += w; sq2[i] += w * w;
    }
  }
#pragma unroll
  for (int sh = 1; sh <= 8; sh <<= 1)
#pragma unroll
    for (int i = 0; i < 4; i++) {
      sum2[i] += __shfl_xor(sum2[i], sh);
      sq2[i] += __shfl_xor(sq2[i], sh);
    }
  float mean[4], rstd[4];
#pragma unroll
  for (int i = 0; i < 4; i++) {
    mean[i] = sum2[i] * (1.0f / 128.0f);
    float var = sq2[i] * (1.0f / 128.0f) - mean[i] * mean[i];
    rstd[i] = rsqrtf(var + 1e-5f);
  }
#pragma unroll
  for (int tt = 0; tt < 8; tt++) {
    int col = tt * 16 + lr;
    float gg = ln2g[col], bb = ln2b[col];
#pragma unroll
    for (int i = 0; i < 4; i++)
      t_lds[(r0 + i) * 136 + col] = f2b((w2r[tt][i] - mean[i]) * rstd[i] * gg + bb);
  }
  __syncthreads();
  f32x4 yacc[8];
#pragma unroll
  for (int tt = 0; tt < 8; tt++) {
    float bv = linb[tt * 16 + lr];
    yacc[tt] = (f32x4){bv, bv, bv, bv};
  }
  for (int s = 0; s < 4; s++) {
    bf16x8 a = *(const bf16x8*)(&t_lds[(m0 + lr) * 136 + s * 32 + lk]);
#pragma unroll
    for (int tt = 0; tt < 8; tt++) {
      bf16x8 b = *(const bf16x8*)(wlin + (size_t)(tt * 16 + lr) * CDIM + s * 32 + lk);
      yacc[tt] = mfma16(a, b, yacc[tt]);
    }
  }
#pragma unroll
  for (int tt = 0; tt < 8; tt++) {
    int col = tt * 16 + lr;
#pragma unroll
    for (int i = 0; i < 4; i++) {
      int node = n0 + r0 + i;
      if (node < NN) outW[(size_t)node * CDIM + col] = w2r[tt][i] + sa4 * yacc[tt][i];
    }
  }
}

extern "C" void kernel_launch(void* const* d_in, const int* in_sizes, int n_in,
                              void* d_out, int out_size, void* d_ws, size_t ws_size,
                              hipStream_t stream) {
  const float* V      = (const float*)d_in[0];
  const float* E      = (const float*)d_in[1];
  const int*   edges  = (const int*)d_in[2];
  const float* fe_w1  = (const float*)d_in[4];
  const float* fe_b1  = (const float*)d_in[5];
  const float* fe_w2  = (const float*)d_in[6];
  const float* fe_b2  = (const float*)d_in[7];
  const float* fe_g   = (const float*)d_in[8];
  const float* fe_be  = (const float*)d_in[9];
  const float* fn_w1  = (const float*)d_in[10];
  const float* fn_b1  = (const float*)d_in[11];
  const float* fn_w2  = (const float*)d_in[12];
  const float* fn_b2  = (const float*)d_in[13];
  const float* fn_g   = (const float*)d_in[14];
  const float* fn_be  = (const float*)d_in[15];
  const float* ln1_g  = (const float*)d_in[16];
  const float* ln1_b  = (const float*)d_in[17];
  const float* ln2_g  = (const float*)d_in[18];
  const float* ln2_b  = (const float*)d_in[19];
  const float* lin_w  = (const float*)d_in[20];
  const float* lin_b  = (const float*)d_in[21];
  const float* Qp     = (const float*)d_in[22];
  const float* q1_w   = (const float*)d_in[23];
  const float* q1_b   = (const float*)d_in[24];
  const float* k1_w   = (const float*)d_in[25];
  const float* k1_b   = (const float*)d_in[26];
  const float* v1_w   = (const float*)d_in[27];
  const float* v1_b   = (const float*)d_in[28];
  const float* mha_in_w  = (const float*)d_in[29];
  const float* mha_in_b  = (const float*)d_in[30];
  const float* mha_out_w = (const float*)d_in[31];
  const float* mha_out_b = (const float*)d_in[32];
  const float* q2_w   = (const float*)d_in[33];
  const float* q2_b   = (const float*)d_in[34];
  const float* k2_w   = (const float*)d_in[35];
  const float* k2_b   = (const float*)d_in[36];
  const float* v2_w   = (const float*)d_in[37];
  const float* v2_b   = (const float*)d_in[38];
  const float* a1 = (const float*)d_in[39];
  const float* a2 = (const float*)d_in[40];
  const float* a3 = (const float*)d_in[41];
  const float* a4 = (const float*)d_in[42];

  char* ws = (char*)d_ws;
  constexpr size_t OFF_WB1  = 0;                          // [256][384] bf16
  constexpr size_t OFF_WB2  = OFF_WB1 + 98304u * 2;       // [128][256] bf16
  constexpr size_t OFF_WN1  = OFF_WB2 + 32768u * 2;       // [256][256] bf16
  constexpr size_t OFF_WN2  = OFF_WN1 + 65536u * 2;       // [128][256] bf16
  constexpr size_t OFF_WKVQ = OFF_WN2 + 32768u * 2;       // [384][128] bf16
  constexpr size_t OFF_BKVQ = OFF_WKVQ + 49152u * 2;      // [384] f32
  constexpr size_t OFF_WLIN = OFF_BKVQ + 2048;            // [128][128] bf16
  constexpr size_t OFF_Q1   = OFF_WLIN + 16384u * 2;      // [64][128] bf16
  constexpr size_t OFF_K2B  = OFF_Q1 + 8192u * 2;         // [64][128] bf16
  constexpr size_t OFF_V2T  = OFF_K2B + 8192u * 2;        // [128][64] bf16
  constexpr size_t OFF_W1   = OFF_V2T + 8192u * 2;        // [64][128] f32
  constexpr size_t OFF_QKV  = OFF_W1 + 8192u * 4;         // [64][384] f32
  constexpr size_t OFF_O    = OFF_QKV + 24576u * 4;       // [64][128] f32
  constexpr size_t OFF_W2   = OFF_O + 8192u * 4;          // [64][128] f32
  constexpr size_t OFF_ACC  = (OFF_W2 + 8192u * 4 + 255) & ~(size_t)255;  // [N][128] f32, later aliased by S [64][NSP] f32
  constexpr size_t OFF_CNT  = OFF_ACC + (size_t)NN * CDIM * 4;
  constexpr size_t OFF_VR   = OFF_CNT + ((NN * 4 + 255) & ~(size_t)255);  // [N][128] f32
  constexpr size_t OFF_W0   = OFF_VR + (size_t)NN * CDIM * 4;             // bf16
  constexpr size_t OFF_K1   = OFF_W0 + (size_t)NN * CDIM * 2;             // bf16
  constexpr size_t OFF_V1   = OFF_K1 + (size_t)NN * CDIM * 2;             // bf16
  constexpr size_t OFF_Q2   = OFF_V1 + (size_t)NN * CDIM * 2;             // bf16

  short* wb1   = (short*)(ws + OFF_WB1);
  short* wb2   = (short*)(ws + OFF_WB2);
  short* wn1   = (short*)(ws + OFF_WN1);
  short* wn2   = (short*)(ws + OFF_WN2);
  short* wkvq  = (short*)(ws + OFF_WKVQ);
  float* bkvq  = (float*)(ws + OFF_BKVQ);
  short* wlin  = (short*)(ws + OFF_WLIN);
  short* q1bf  = (short*)(ws + OFF_Q1);
  short* k2bf  = (short*)(ws + OFF_K2B);
  short* v2tbf = (short*)(ws + OFF_V2T);
  float* W1    = (float*)(ws + OFF_W1);
  float* qkv   = (float*)(ws + OFF_QKV);
  float* o     = (float*)(ws + OFF_O);
  float* W2    = (float*)(ws + OFF_W2);
  float* accn  = (float*)(ws + OFF_ACC);
  float* S     = (float*)(ws + OFF_ACC);  // alias: acc dead after node_kernel
  float* cnt   = (float*)(ws + OFF_CNT);
  float* Vr    = (float*)(ws + OFF_VR);
  short* W0bf  = (short*)(ws + OFF_W0);
  short* K1bf  = (short*)(ws + OFF_K1);
  short* V1bf  = (short*)(ws + OFF_V1);
  short* Q2bf  = (short*)(ws + OFF_Q2);

  float* outW = (float*)d_out;
  float* outE = outW + (size_t)NN * CDIM;

  hipMemsetAsync(accn, 0, (size_t)NN * CDIM * 4, stream);
  hipMemsetAsync(cnt, 0, (size_t)NN * 4, stream);
  hipMemsetAsync(W1, 0, 8192u * 4, stream);

  prep_kernel<<<256, 256, 0, stream>>>(fe_w1, fe_w2, fn_w1, fn_w2,
                                       k1_w, v1_w, q2_w, k1_b, v1_b, q2_b,
                                       lin_w, wb1, wb2, wn1, wn2, wkvq, bkvq, wlin);
  q1_kernel<<<32, 256, 0, stream>>>(Qp, q1_w, q1_b, q1bf);
  edge_kernel<<<NEDGE / 64, 256, 0, stream>>>(V, E, edges, wb1, fe_b1, wb2, fe_b2,
                                              fe_g, fe_be, a2, accn, cnt, outE);
  node_kernel<<<(NN + 63) / 64, 256, 0, stream>>>(V, accn, cnt, wn1, fn_b1, wn2, fn_b2,
                                                  fn_g, fn_be, ln1_g, ln1_b, a1, Vr, W0bf);
  kvq_kernel<<<(NN + 63) / 64, 256, 0, stream>>>(W0bf, wkvq, bkvq, K1bf, V1bf, Q2bf);
  s_kernel<<<(NN + 255) / 256, 256, 0, stream>>>(q1bf, K1bf, S);
  softmax_kernel<<<64, 256, 0, stream>>>(S);
  w1_kernel<<<128, 256, 0, stream>>>(S, V1bf, W1);
  qkv_kernel<<<96, 256, 0, stream>>>(W1, mha_in_w, mha_in_b, qkv);
  heads_kernel<<<4, 256, 0, stream>>>(qkv, o);
  w2_kernel<<<32, 256, 0, stream>>>(o, mha_out_w, mha_out_b, W2);
  kv2_kernel<<<64, 256, 0, stream>>>(W2, k2_w, k2_b, v2_w, v2_b, k2bf, v2tbf);
  g_kernel<<<(NN + 63) / 64, 256, 0, stream>>>(Q2bf, k2bf, v2tbf, wlin, lin_b,
                                               ln2_g, ln2_b, Vr, a3, a4, outW);
}